// Round 5
// baseline (101.136 us; speedup 1.0000x reference)
//
#include <hip/hip_runtime.h>

typedef float f32x4 __attribute__((ext_vector_type(4)));

// Closed-form polar projection of 2x2 W (= U @ Vh from SVD), then compose
// with phase rotation R(phi) = [[c,-s],[s,c]]:  M = R * polar(W).
__device__ __forceinline__ void compute_M(const float4* __restrict__ W,
                                          const float* __restrict__ phase,
                                          int g,
                                          float& m00, float& m01,
                                          float& m10, float& m11) {
    float4 w = W[g];                 // [a b; c d] row-major
    float a = w.x, b = w.y, c = w.z, d = w.w;
    float det = a * d - b * c;
    float q00, q01, q10, q11;
    if (det >= 0.0f) {               // nearest rotation
        float p = a + d, q = b - c;
        float inv = rsqrtf(p * p + q * q);
        q00 = p * inv;  q01 = q * inv;
        q10 = -q * inv; q11 = p * inv;
    } else {                         // nearest reflection
        float p = a - d, q = b + c;
        float inv = rsqrtf(p * p + q * q);
        q00 = p * inv; q01 = q * inv;
        q10 = q * inv; q11 = -p * inv;
    }
    float cs, sn;
    __sincosf(phase[g], &sn, &cs);
    m00 = cs * q00 - sn * q10;
    m01 = cs * q01 - sn * q11;
    m10 = sn * q00 + cs * q10;
    m11 = sn * q01 + cs * q11;
}

// Windowed streaming kernel (R4 structure), nt flags REMOVED (A/B vs R4).
// Each block owns contiguous 1024-float4 (16 KB) windows; thread t covers
// slots t, t+256, t+512, t+768 -> 4 fully-coalesced loads 4 KB apart.
// A window = 2 C-rows, so slot group indices are loop-invariant:
// even slots use groups (2t, 2t+1); odd slots groups (2t+512, 2t+513).
__global__ __launch_bounds__(256) void bsu_win(const f32x4* __restrict__ x,
                                               const float4* __restrict__ W,
                                               const float* __restrict__ phase,
                                               f32x4* __restrict__ y,
                                               int nwin, int gmask) {
    int t = threadIdx.x;
    int gA = (2 * t) & gmask;            // even slots: groups gA, gA+1
    int gB = (2 * (t + 256)) & gmask;    // odd slots:  groups gB, gB+1

    float a00, a01, a10, a11;  // M[gA]
    float c00, c01, c10, c11;  // M[gA+1]
    float e00, e01, e10, e11;  // M[gB]
    float f00, f01, f10, f11;  // M[gB+1]
    compute_M(W, phase, gA,     a00, a01, a10, a11);
    compute_M(W, phase, gA + 1, c00, c01, c10, c11);
    compute_M(W, phase, gB,     e00, e01, e10, e11);
    compute_M(W, phase, gB + 1, f00, f01, f10, f11);

    for (int w = blockIdx.x; w < nwin; w += gridDim.x) {
        int base = w * 1024 + t;
        f32x4 v0 = x[base];
        f32x4 v1 = x[base + 256];
        f32x4 v2 = x[base + 512];
        f32x4 v3 = x[base + 768];
        f32x4 o0, o1, o2, o3;
        o0.x = a00 * v0.x + a01 * v0.y;  o0.y = a10 * v0.x + a11 * v0.y;
        o0.z = c00 * v0.z + c01 * v0.w;  o0.w = c10 * v0.z + c11 * v0.w;
        o1.x = e00 * v1.x + e01 * v1.y;  o1.y = e10 * v1.x + e11 * v1.y;
        o1.z = f00 * v1.z + f01 * v1.w;  o1.w = f10 * v1.z + f11 * v1.w;
        o2.x = a00 * v2.x + a01 * v2.y;  o2.y = a10 * v2.x + a11 * v2.y;
        o2.z = c00 * v2.z + c01 * v2.w;  o2.w = c10 * v2.z + c11 * v2.w;
        o3.x = e00 * v3.x + e01 * v3.y;  o3.y = e10 * v3.x + e11 * v3.y;
        o3.z = f00 * v3.z + f01 * v3.w;  o3.w = f10 * v3.z + f11 * v3.w;
        y[base]       = o0;
        y[base + 256] = o1;
        y[base + 512] = o2;
        y[base + 768] = o3;
    }
}

// Fallback: simple grid-stride, loop-invariant group (generic shapes).
__global__ __launch_bounds__(256) void bsu_fused(const f32x4* __restrict__ x,
                                                 const float4* __restrict__ W,
                                                 const float* __restrict__ phase,
                                                 f32x4* __restrict__ y,
                                                 int n4, int gmask) {
    int i0 = blockIdx.x * 256 + threadIdx.x;
    int stride = gridDim.x * 256;
    int g0 = (2 * i0) & gmask;

    float a00, a01, a10, a11;
    float b00, b01, b10, b11;
    compute_M(W, phase, g0,     a00, a01, a10, a11);
    compute_M(W, phase, g0 + 1, b00, b01, b10, b11);

    for (int i = i0; i < n4; i += stride) {
        f32x4 v = x[i];
        f32x4 o;
        o.x = a00 * v.x + a01 * v.y;
        o.y = a10 * v.x + a11 * v.y;
        o.z = b00 * v.z + b01 * v.w;
        o.w = b10 * v.z + b11 * v.w;
        y[i] = o;
    }
}

extern "C" void kernel_launch(void* const* d_in, const int* in_sizes, int n_in,
                              void* d_out, int out_size, void* d_ws, size_t ws_size,
                              hipStream_t stream) {
    const float* x     = (const float*)d_in[0];   // [B,T,C] f32
    const float* Wp    = (const float*)d_in[1];   // [G,2,2] f32
    const float* phase = (const float*)d_in[2];   // [G] f32
    float* y = (float*)d_out;

    int G = in_sizes[2];             // 1024
    int n = in_sizes[0];             // B*T*C = 67,108,864
    int n4 = n / 4;                  // 16,777,216 float4s
    int row4 = G / 2;                // float4s per C-row (512)

    bool pow2G = (G & (G - 1)) == 0;
    if (pow2G && row4 > 0 && (1024 % row4) == 0 && (n4 % 1024) == 0) {
        int nwin = n4 / 1024;        // 16384
        bsu_win<<<2048, 256, 0, stream>>>((const f32x4*)x, (const float4*)Wp,
                                          phase, (f32x4*)y, nwin, G - 1);
    } else {
        int blocks = 2048;
        if (!pow2G || (blocks * 256) % row4 != 0) blocks = (n4 + 255) / 256;
        bsu_fused<<<blocks, 256, 0, stream>>>((const f32x4*)x,
                                              (const float4*)Wp, phase,
                                              (f32x4*)y, n4, G - 1);
    }
}

// Round 6
// 91.762 us; speedup vs baseline: 1.1021x; 1.1021x over previous
//
#include <hip/hip_runtime.h>

typedef float f32x4 __attribute__((ext_vector_type(4)));

// Closed-form polar projection of 2x2 W (= U @ Vh from SVD), then compose
// with phase rotation R(phi) = [[c,-s],[s,c]]:  M = R * polar(W).
__device__ __forceinline__ void compute_M(const float4* __restrict__ W,
                                          const float* __restrict__ phase,
                                          int g,
                                          float& m00, float& m01,
                                          float& m10, float& m11) {
    float4 w = W[g];                 // [a b; c d] row-major
    float a = w.x, b = w.y, c = w.z, d = w.w;
    float det = a * d - b * c;
    float q00, q01, q10, q11;
    if (det >= 0.0f) {               // nearest rotation
        float p = a + d, q = b - c;
        float inv = rsqrtf(p * p + q * q);
        q00 = p * inv;  q01 = q * inv;
        q10 = -q * inv; q11 = p * inv;
    } else {                         // nearest reflection
        float p = a - d, q = b + c;
        float inv = rsqrtf(p * p + q * q);
        q00 = p * inv; q01 = q * inv;
        q10 = q * inv; q11 = -p * inv;
    }
    float cs, sn;
    __sincosf(phase[g], &sn, &cs);
    m00 = cs * q00 - sn * q10;
    m01 = cs * q01 - sn * q11;
    m10 = sn * q00 + cs * q10;
    m11 = sn * q01 + cs * q11;
}

// Windowed streaming kernel with nt flags (R4 best) + 2-stage register
// pipeline: issue window w+1's 4 loads BEFORE computing/storing window w,
// so each wave keeps the next read burst in flight while the write burst
// drains (vmcnt counts loads AND stores in FIFO order — without prefetch
// the next loads serialize behind the store drain).
__global__ __launch_bounds__(256) void bsu_win(const f32x4* __restrict__ x,
                                               const float4* __restrict__ W,
                                               const float* __restrict__ phase,
                                               f32x4* __restrict__ y,
                                               int nwin, int gmask) {
    int t = threadIdx.x;
    int gA = (2 * t) & gmask;            // even slots: groups gA, gA+1
    int gB = (2 * (t + 256)) & gmask;    // odd slots:  groups gB, gB+1

    float a00, a01, a10, a11;  // M[gA]
    float c00, c01, c10, c11;  // M[gA+1]
    float e00, e01, e10, e11;  // M[gB]
    float f00, f01, f10, f11;  // M[gB+1]
    compute_M(W, phase, gA,     a00, a01, a10, a11);
    compute_M(W, phase, gA + 1, c00, c01, c10, c11);
    compute_M(W, phase, gB,     e00, e01, e10, e11);
    compute_M(W, phase, gB + 1, f00, f01, f10, f11);

    int stride = gridDim.x;
    int w = blockIdx.x;
    if (w >= nwin) return;

    int base = w * 1024 + t;
    f32x4 v0 = __builtin_nontemporal_load(&x[base]);
    f32x4 v1 = __builtin_nontemporal_load(&x[base + 256]);
    f32x4 v2 = __builtin_nontemporal_load(&x[base + 512]);
    f32x4 v3 = __builtin_nontemporal_load(&x[base + 768]);

    while (true) {
        int wn = w + stride;
        f32x4 n0, n1, n2, n3;
        bool has = (wn < nwin);
        if (has) {                   // prefetch next window FIRST
            int nb = wn * 1024 + t;
            n0 = __builtin_nontemporal_load(&x[nb]);
            n1 = __builtin_nontemporal_load(&x[nb + 256]);
            n2 = __builtin_nontemporal_load(&x[nb + 512]);
            n3 = __builtin_nontemporal_load(&x[nb + 768]);
        }
        f32x4 o0, o1, o2, o3;
        o0.x = a00 * v0.x + a01 * v0.y;  o0.y = a10 * v0.x + a11 * v0.y;
        o0.z = c00 * v0.z + c01 * v0.w;  o0.w = c10 * v0.z + c11 * v0.w;
        o1.x = e00 * v1.x + e01 * v1.y;  o1.y = e10 * v1.x + e11 * v1.y;
        o1.z = f00 * v1.z + f01 * v1.w;  o1.w = f10 * v1.z + f11 * v1.w;
        o2.x = a00 * v2.x + a01 * v2.y;  o2.y = a10 * v2.x + a11 * v2.y;
        o2.z = c00 * v2.z + c01 * v2.w;  o2.w = c10 * v2.z + c11 * v2.w;
        o3.x = e00 * v3.x + e01 * v3.y;  o3.y = e10 * v3.x + e11 * v3.y;
        o3.z = f00 * v3.z + f01 * v3.w;  o3.w = f10 * v3.z + f11 * v3.w;
        __builtin_nontemporal_store(o0, &y[base]);
        __builtin_nontemporal_store(o1, &y[base + 256]);
        __builtin_nontemporal_store(o2, &y[base + 512]);
        __builtin_nontemporal_store(o3, &y[base + 768]);
        if (!has) break;
        w = wn;
        base = wn * 1024 + t;
        v0 = n0; v1 = n1; v2 = n2; v3 = n3;
    }
}

// Fallback: simple grid-stride, loop-invariant group (generic shapes).
__global__ __launch_bounds__(256) void bsu_fused(const f32x4* __restrict__ x,
                                                 const float4* __restrict__ W,
                                                 const float* __restrict__ phase,
                                                 f32x4* __restrict__ y,
                                                 int n4, int gmask) {
    int i0 = blockIdx.x * 256 + threadIdx.x;
    int stride = gridDim.x * 256;
    int g0 = (2 * i0) & gmask;

    float a00, a01, a10, a11;
    float b00, b01, b10, b11;
    compute_M(W, phase, g0,     a00, a01, a10, a11);
    compute_M(W, phase, g0 + 1, b00, b01, b10, b11);

    for (int i = i0; i < n4; i += stride) {
        f32x4 v = __builtin_nontemporal_load(&x[i]);
        f32x4 o;
        o.x = a00 * v.x + a01 * v.y;
        o.y = a10 * v.x + a11 * v.y;
        o.z = b00 * v.z + b01 * v.w;
        o.w = b10 * v.z + b11 * v.w;
        __builtin_nontemporal_store(o, &y[i]);
    }
}

extern "C" void kernel_launch(void* const* d_in, const int* in_sizes, int n_in,
                              void* d_out, int out_size, void* d_ws, size_t ws_size,
                              hipStream_t stream) {
    const float* x     = (const float*)d_in[0];   // [B,T,C] f32
    const float* Wp    = (const float*)d_in[1];   // [G,2,2] f32
    const float* phase = (const float*)d_in[2];   // [G] f32
    float* y = (float*)d_out;

    int G = in_sizes[2];             // 1024
    int n = in_sizes[0];             // B*T*C = 67,108,864
    int n4 = n / 4;                  // 16,777,216 float4s
    int row4 = G / 2;                // float4s per C-row (512)

    bool pow2G = (G & (G - 1)) == 0;
    if (pow2G && row4 > 0 && (1024 % row4) == 0 && (n4 % 1024) == 0) {
        int nwin = n4 / 1024;        // 16384
        bsu_win<<<2048, 256, 0, stream>>>((const f32x4*)x, (const float4*)Wp,
                                          phase, (f32x4*)y, nwin, G - 1);
    } else {
        int blocks = 2048;
        if (!pow2G || (blocks * 256) % row4 != 0) blocks = (n4 + 255) / 256;
        bsu_fused<<<blocks, 256, 0, stream>>>((const f32x4*)x,
                                              (const float4*)Wp, phase,
                                              (f32x4*)y, n4, G - 1);
    }
}